// Round 1
// baseline (1174.552 us; speedup 1.0000x reference)
//
#include <hip/hip_runtime.h>
#include <hip/hip_bf16.h>

#define N_NODES 100000
#define N_EDGES 1600000

// ---------------------------------------------------------------- CSR build
__global__ void zero_int(int* p, int n) {
    int i = blockIdx.x * blockDim.x + threadIdx.x;
    if (i < n) p[i] = 0;
}

__global__ void count_deg(const int* __restrict__ dst, int* __restrict__ deg, int E) {
    int i = blockIdx.x * blockDim.x + threadIdx.x;
    if (i < E) atomicAdd(&deg[dst[i]], 1);
}

// single-block exclusive scan: row_ptr[0]=0, row_ptr[i+1]=sum deg[0..i]
__global__ void scan_deg(const int* __restrict__ deg, int* __restrict__ row_ptr, int N) {
    __shared__ int wsum[16];
    __shared__ int s_running;
    const int tid = threadIdx.x;
    const int lane = tid & 63;
    const int wid = tid >> 6;
    if (tid == 0) { s_running = 0; row_ptr[0] = 0; }
    __syncthreads();
    for (int base = 0; base < N; base += 1024) {
        int i = base + tid;
        int v = (i < N) ? deg[i] : 0;
        int x = v;
        #pragma unroll
        for (int off = 1; off < 64; off <<= 1) {
            int y = __shfl_up(x, off, 64);
            if (lane >= off) x += y;
        }
        if (lane == 63) wsum[wid] = x;
        __syncthreads();
        if (wid == 0) {
            int s = (lane < 16) ? wsum[lane] : 0;
            #pragma unroll
            for (int off = 1; off < 16; off <<= 1) {
                int y = __shfl_up(s, off, 64);
                if (lane >= off) s += y;
            }
            if (lane < 16) wsum[lane] = s;
        }
        __syncthreads();
        int run = s_running;
        int offset = run + ((wid > 0) ? wsum[wid - 1] : 0);
        if (i < N) row_ptr[i + 1] = offset + x;
        __syncthreads();
        if (tid == 0) s_running = run + wsum[15];
        __syncthreads();
    }
}

__global__ void copy_int(const int* __restrict__ a, int* __restrict__ b, int n) {
    int i = blockIdx.x * blockDim.x + threadIdx.x;
    if (i < n) b[i] = a[i];
}

__global__ void scatter_edges(const int* __restrict__ src, const int* __restrict__ dst,
                              int* __restrict__ cursor, int* __restrict__ e_src, int E) {
    int i = blockIdx.x * blockDim.x + threadIdx.x;
    if (i < E) {
        int p = atomicAdd(&cursor[dst[i]], 1);
        e_src[p] = src[i];
    }
}

// ---------------------------------------------------------------- GEMM  C[N,K] = A[gather,0:128] @ W[128,K]
template <int K, int NT>
__global__ void gemm_x128(const float* __restrict__ A, const float* __restrict__ W,
                          float* __restrict__ C, const int* __restrict__ gather, int N) {
    constexpr int ROWS = 16;
    constexpr int COLS = (K + NT - 1) / NT;
    __shared__ float4 As[ROWS][32];
    __shared__ int ridx[ROWS];
    const int tid = threadIdx.x;
    const int r0 = blockIdx.x * ROWS;

    if (tid < ROWS) {
        int row = r0 + tid;
        int pr = 0;
        if (row < N) pr = gather ? gather[row] : row;
        ridx[tid] = pr;
    }
    __syncthreads();
    const float4* A4 = (const float4*)A;
    #pragma unroll
    for (int i = tid; i < ROWS * 32; i += NT) {
        int r = i >> 5, k4 = i & 31;
        As[r][k4] = A4[ridx[r] * 32 + k4];
    }
    __syncthreads();

    float acc[COLS][ROWS];
    #pragma unroll
    for (int j = 0; j < COLS; ++j)
        #pragma unroll
        for (int r = 0; r < ROWS; ++r) acc[j][r] = 0.f;

    int c[COLS];
    #pragma unroll
    for (int j = 0; j < COLS; ++j) c[j] = tid + j * NT;

    for (int k4 = 0; k4 < 32; ++k4) {
        float w[COLS][4];
        #pragma unroll
        for (int j = 0; j < COLS; ++j)
            #pragma unroll
            for (int jj = 0; jj < 4; ++jj)
                w[j][jj] = (c[j] < K) ? W[(k4 * 4 + jj) * K + c[j]] : 0.f;
        #pragma unroll
        for (int r = 0; r < ROWS; ++r) {
            float4 a = As[r][k4];
            #pragma unroll
            for (int j = 0; j < COLS; ++j) {
                acc[j][r] += a.x * w[j][0];
                acc[j][r] += a.y * w[j][1];
                acc[j][r] += a.z * w[j][2];
                acc[j][r] += a.w * w[j][3];
            }
        }
    }

    #pragma unroll
    for (int r = 0; r < ROWS; ++r) {
        int row = r0 + r;
        if (row < N) {
            #pragma unroll
            for (int j = 0; j < COLS; ++j)
                if (c[j] < K) C[row * K + c[j]] = acc[j][r];
        }
    }
}

// ---------------------------------------------------------------- per-node attention dot products
// el[n,h] = sum_d feat[n, h*D+d] * al[h*D+d]   (er with ar)
template <int H, int D, int HD, int HDP, int P2>
__global__ void compute_elr(const float* __restrict__ feat, const float* __restrict__ al,
                            const float* __restrict__ ar, float* __restrict__ el,
                            float* __restrict__ er) {
    const int n = blockIdx.x;
    const int t = threadIdx.x;
    __shared__ float sa[HDP], sb[HDP];
    float f = 0.f, a = 0.f, b = 0.f;
    if (t < HD) {
        f = feat[n * HD + t];
        a = al[t];
        b = ar[t];
    }
    sa[t] = f * a;
    sb[t] = f * b;
    for (int s = P2 / 2; s >= 1; s >>= 1) {
        __syncthreads();
        if (t < HD) {
            int d = t % D;
            if (d < s && d + s < D) {
                sa[t] += sa[t + s];
                sb[t] += sb[t + s];
            }
        }
    }
    __syncthreads();
    if (t < HD && (t % D) == 0) {
        int h = t / D;
        el[n * H + h] = sa[t];
        er[n * H + h] = sb[t];
    }
}

// ---------------------------------------------------------------- layer-1 gather: softmax-weighted aggregate + bias + ELU
__global__ void gat_gather1(const float* __restrict__ feat, const float* __restrict__ el,
                            const float* __restrict__ er, const int* __restrict__ row_ptr,
                            const int* __restrict__ e_src, const float* __restrict__ bias,
                            float* __restrict__ out) {
    const int n = blockIdx.x;
    const int t = threadIdx.x;      // 128 threads, t = h*32 + d
    const int h = t >> 5;
    const int start = row_ptr[n];
    const int end = row_ptr[n + 1];
    const float ern = er[n * 4 + h];
    float s = 0.f, acc = 0.f;
    for (int i = start; i < end; ++i) {
        int sv = e_src[i];
        float e = el[sv * 4 + h] + ern;
        e = (e > 0.f) ? e : 0.2f * e;
        float w = __expf(e);
        s += w;
        acc += w * feat[sv * 128 + t];
    }
    float o = acc / fmaxf(s, 1e-9f) + bias[t];
    o = (o > 0.f) ? o : (__expf(o) - 1.f);  // ELU(alpha=1)
    out[n * 128 + t] = o;
}

// ---------------------------------------------------------------- layer-2 gather: aggregate + bias + head-mean
__global__ void gat_gather2(const float* __restrict__ feat, const float* __restrict__ el,
                            const float* __restrict__ er, const int* __restrict__ row_ptr,
                            const int* __restrict__ e_src, const float* __restrict__ bias,
                            float* __restrict__ out) {
    const int n = blockIdx.x;
    const int t = threadIdx.x;      // 192 threads, 188 active: t = h*47 + d
    __shared__ float tmp[192];
    float o = 0.f;
    if (t < 188) {
        const int h = t / 47;
        const int start = row_ptr[n];
        const int end = row_ptr[n + 1];
        const float ern = er[n * 4 + h];
        float s = 0.f, acc = 0.f;
        for (int i = start; i < end; ++i) {
            int sv = e_src[i];
            float e = el[sv * 4 + h] + ern;
            e = (e > 0.f) ? e : 0.2f * e;
            float w = __expf(e);
            s += w;
            acc += w * feat[sv * 188 + t];
        }
        o = acc / fmaxf(s, 1e-9f) + bias[t];
    }
    tmp[t] = o;
    __syncthreads();
    if (t < 47)
        out[n * 47 + t] = 0.25f * (tmp[t] + tmp[t + 47] + tmp[t + 94] + tmp[t + 141]);
}

// ---------------------------------------------------------------- launcher
extern "C" void kernel_launch(void* const* d_in, const int* in_sizes, int n_in,
                              void* d_out, int out_size, void* d_ws, size_t ws_size,
                              hipStream_t stream) {
    const int N = N_NODES, E = N_EDGES;
    const float* x    = (const float*)d_in[0];
    const int*   src  = (const int*)d_in[1];
    const int*   dst  = (const int*)d_in[2];
    const int*   inv  = (const int*)d_in[3];
    const float* W1   = (const float*)d_in[4];
    const float* al1  = (const float*)d_in[5];
    const float* ar1  = (const float*)d_in[6];
    const float* b1   = (const float*)d_in[7];
    const float* W2   = (const float*)d_in[8];
    const float* al2  = (const float*)d_in[9];
    const float* ar2  = (const float*)d_in[10];
    const float* b2   = (const float*)d_in[11];
    float* out = (float*)d_out;

    // workspace carve (all 256B-aligned)
    char* p = (char*)d_ws;
    auto carve = [&](size_t bytes) {
        char* q = p;
        p += (bytes + 255) & ~size_t(255);
        return q;
    };
    float* feat    = (float*)carve((size_t)N * 188 * 4);  // layer1 uses stride 128, layer2 stride 188
    float* hbuf    = (float*)carve((size_t)N * 128 * 4);
    float* el      = (float*)carve((size_t)N * 4 * 4);
    float* er      = (float*)carve((size_t)N * 4 * 4);
    int*   deg     = (int*)carve((size_t)N * 4);
    int*   row_ptr = (int*)carve((size_t)(N + 1) * 4);
    int*   cursor  = (int*)carve((size_t)N * 4);
    int*   e_src   = (int*)carve((size_t)E * 4);

    // ---- CSR build (per launch; ws is re-poisoned each call) ----
    zero_int<<<(N + 255) / 256, 256, 0, stream>>>(deg, N);
    count_deg<<<(E + 255) / 256, 256, 0, stream>>>(dst, deg, E);
    scan_deg<<<1, 1024, 0, stream>>>(deg, row_ptr, N);
    copy_int<<<(N + 255) / 256, 256, 0, stream>>>(row_ptr, cursor, N);
    scatter_edges<<<(E + 255) / 256, 256, 0, stream>>>(src, dst, cursor, e_src, E);

    // ---- layer 1 ----
    gemm_x128<128, 64><<<(N + 15) / 16, 64, 0, stream>>>(x, W1, feat, nullptr, N);
    compute_elr<4, 32, 128, 128, 32><<<N, 128, 0, stream>>>(feat, al1, ar1, el, er);
    gat_gather1<<<N, 128, 0, stream>>>(feat, el, er, row_ptr, e_src, b1, hbuf);

    // ---- layer 2 (input rows gathered through inverse_idx) ----
    gemm_x128<188, 128><<<(N + 15) / 16, 128, 0, stream>>>(hbuf, W2, feat, inv, N);
    compute_elr<4, 47, 188, 192, 64><<<N, 192, 0, stream>>>(feat, al2, ar2, el, er);
    gat_gather2<<<N, 192, 0, stream>>>(feat, el, er, row_ptr, e_src, b2, out);
}

// Round 2
// 997.559 us; speedup vs baseline: 1.1774x; 1.1774x over previous
//
#include <hip/hip_runtime.h>
#include <hip/hip_bf16.h>
#include <hip/hip_fp16.h>

#define N_NODES 100000
#define N_EDGES 1600000

// ---------------------------------------------------------------- CSR build
__global__ void zero_int(int* p, int n) {
    int i = blockIdx.x * blockDim.x + threadIdx.x;
    if (i < n) p[i] = 0;
}

__global__ void count_deg(const int* __restrict__ dst, int* __restrict__ deg, int E) {
    int i = blockIdx.x * blockDim.x + threadIdx.x;
    if (i < E) atomicAdd(&deg[dst[i]], 1);
}

// single-block exclusive scan: row_ptr[0]=0, row_ptr[i+1]=sum deg[0..i]
__global__ void scan_deg(const int* __restrict__ deg, int* __restrict__ row_ptr, int N) {
    __shared__ int wsum[16];
    __shared__ int s_running;
    const int tid = threadIdx.x;
    const int lane = tid & 63;
    const int wid = tid >> 6;
    if (tid == 0) { s_running = 0; row_ptr[0] = 0; }
    __syncthreads();
    for (int base = 0; base < N; base += 1024) {
        int i = base + tid;
        int v = (i < N) ? deg[i] : 0;
        int x = v;
        #pragma unroll
        for (int off = 1; off < 64; off <<= 1) {
            int y = __shfl_up(x, off, 64);
            if (lane >= off) x += y;
        }
        if (lane == 63) wsum[wid] = x;
        __syncthreads();
        if (wid == 0) {
            int s = (lane < 16) ? wsum[lane] : 0;
            #pragma unroll
            for (int off = 1; off < 16; off <<= 1) {
                int y = __shfl_up(s, off, 64);
                if (lane >= off) s += y;
            }
            if (lane < 16) wsum[lane] = s;
        }
        __syncthreads();
        int run = s_running;
        int offset = run + ((wid > 0) ? wsum[wid - 1] : 0);
        if (i < N) row_ptr[i + 1] = offset + x;
        __syncthreads();
        if (tid == 0) s_running = run + wsum[15];
        __syncthreads();
    }
}

__global__ void copy_int(const int* __restrict__ a, int* __restrict__ b, int n) {
    int i = blockIdx.x * blockDim.x + threadIdx.x;
    if (i < n) b[i] = a[i];
}

__global__ void scatter_edges(const int* __restrict__ src, const int* __restrict__ dst,
                              int* __restrict__ cursor, int* __restrict__ e_src,
                              int* __restrict__ e_dst, int E) {
    int i = blockIdx.x * blockDim.x + threadIdx.x;
    if (i < E) {
        int d = dst[i];
        int p = atomicAdd(&cursor[d], 1);
        e_src[p] = src[i];
        e_dst[p] = d;
    }
}

// ---------------------------------------------------------------- GEMM  C[N,K] = A[gather,0:128] @ W[128,K]
template <int K, int NT>
__global__ void gemm_x128(const float* __restrict__ A, const float* __restrict__ W,
                          float* __restrict__ C, const int* __restrict__ gather, int N) {
    constexpr int ROWS = 16;
    constexpr int COLS = (K + NT - 1) / NT;
    __shared__ float4 As[ROWS][32];
    __shared__ int ridx[ROWS];
    const int tid = threadIdx.x;
    const int r0 = blockIdx.x * ROWS;

    if (tid < ROWS) {
        int row = r0 + tid;
        int pr = 0;
        if (row < N) pr = gather ? gather[row] : row;
        ridx[tid] = pr;
    }
    __syncthreads();
    const float4* A4 = (const float4*)A;
    #pragma unroll
    for (int i = tid; i < ROWS * 32; i += NT) {
        int r = i >> 5, k4 = i & 31;
        As[r][k4] = A4[ridx[r] * 32 + k4];
    }
    __syncthreads();

    float acc[COLS][ROWS];
    #pragma unroll
    for (int j = 0; j < COLS; ++j)
        #pragma unroll
        for (int r = 0; r < ROWS; ++r) acc[j][r] = 0.f;

    int c[COLS];
    #pragma unroll
    for (int j = 0; j < COLS; ++j) c[j] = tid + j * NT;

    for (int k4 = 0; k4 < 32; ++k4) {
        float w[COLS][4];
        #pragma unroll
        for (int j = 0; j < COLS; ++j)
            #pragma unroll
            for (int jj = 0; jj < 4; ++jj)
                w[j][jj] = (c[j] < K) ? W[(k4 * 4 + jj) * K + c[j]] : 0.f;
        #pragma unroll
        for (int r = 0; r < ROWS; ++r) {
            float4 a = As[r][k4];
            #pragma unroll
            for (int j = 0; j < COLS; ++j) {
                acc[j][r] += a.x * w[j][0];
                acc[j][r] += a.y * w[j][1];
                acc[j][r] += a.z * w[j][2];
                acc[j][r] += a.w * w[j][3];
            }
        }
    }

    #pragma unroll
    for (int r = 0; r < ROWS; ++r) {
        int row = r0 + r;
        if (row < N) {
            #pragma unroll
            for (int j = 0; j < COLS; ++j)
                if (c[j] < K) C[row * K + c[j]] = acc[j][r];
        }
    }
}

// ---------------------------------------------------------------- per-node attention dot products
template <int H, int D, int HD, int HDP, int P2>
__global__ void compute_elr(const float* __restrict__ feat, const float* __restrict__ al,
                            const float* __restrict__ ar, float* __restrict__ el,
                            float* __restrict__ er) {
    const int n = blockIdx.x;
    const int t = threadIdx.x;
    __shared__ float sa[HDP], sb[HDP];
    float f = 0.f, a = 0.f, b = 0.f;
    if (t < HD) {
        f = feat[n * HD + t];
        a = al[t];
        b = ar[t];
    }
    sa[t] = f * a;
    sb[t] = f * b;
    for (int s = P2 / 2; s >= 1; s >>= 1) {
        __syncthreads();
        if (t < HD) {
            int d = t % D;
            if (d < s && d + s < D) {
                sa[t] += sa[t + s];
                sb[t] += sb[t + s];
            }
        }
    }
    __syncthreads();
    if (t < HD && (t % D) == 0) {
        int h = t / D;
        el[n * H + h] = sa[t];
        er[n * H + h] = sb[t];
    }
}

// ---------------------------------------------------------------- per-edge attention weights (CSR order, fp16)
// w[i*4+h] = exp(leakyrelu(el[e_src[i]][h] + er[e_dst[i]][h]))
__global__ void edge_weights(const int* __restrict__ e_src, const int* __restrict__ e_dst,
                             const float* __restrict__ el, const float* __restrict__ er,
                             __half* __restrict__ w, int E) {
    int i = blockIdx.x * blockDim.x + threadIdx.x;
    if (i >= E) return;
    int s = e_src[i], d = e_dst[i];
    float4 a = ((const float4*)el)[s];
    float4 b = ((const float4*)er)[d];
    float e0 = a.x + b.x; e0 = (e0 > 0.f) ? e0 : 0.2f * e0;
    float e1 = a.y + b.y; e1 = (e1 > 0.f) ? e1 : 0.2f * e1;
    float e2 = a.z + b.z; e2 = (e2 > 0.f) ? e2 : 0.2f * e2;
    float e3 = a.w + b.w; e3 = (e3 > 0.f) ? e3 : 0.2f * e3;
    __half2* w2 = (__half2*)w;
    w2[i * 2 + 0] = __floats2half2_rn(__expf(e0), __expf(e1));
    w2[i * 2 + 1] = __floats2half2_rn(__expf(e2), __expf(e3));
}

// ---------------------------------------------------------------- layer-1 gather: weighted aggregate + bias + ELU
__global__ void gat_gather1(const float* __restrict__ feat, const __half* __restrict__ w,
                            const int* __restrict__ row_ptr, const int* __restrict__ e_src,
                            const float* __restrict__ bias, float* __restrict__ out) {
    const int n = blockIdx.x;
    const int t = threadIdx.x;      // 128 threads, t = h*32 + d
    const int h = t >> 5;
    const int start = row_ptr[n];
    const int end = row_ptr[n + 1];
    float s = 0.f, acc = 0.f;
    int i = start;
    for (; i + 4 <= end; i += 4) {
        int sv0 = e_src[i + 0];
        int sv1 = e_src[i + 1];
        int sv2 = e_src[i + 2];
        int sv3 = e_src[i + 3];
        float w0 = __half2float(w[(i + 0) * 4 + h]);
        float w1 = __half2float(w[(i + 1) * 4 + h]);
        float w2 = __half2float(w[(i + 2) * 4 + h]);
        float w3 = __half2float(w[(i + 3) * 4 + h]);
        float f0 = feat[(size_t)sv0 * 128 + t];
        float f1 = feat[(size_t)sv1 * 128 + t];
        float f2 = feat[(size_t)sv2 * 128 + t];
        float f3 = feat[(size_t)sv3 * 128 + t];
        s += (w0 + w1) + (w2 + w3);
        acc += w0 * f0;
        acc += w1 * f1;
        acc += w2 * f2;
        acc += w3 * f3;
    }
    for (; i < end; ++i) {
        int sv = e_src[i];
        float ww = __half2float(w[i * 4 + h]);
        s += ww;
        acc += ww * feat[(size_t)sv * 128 + t];
    }
    float o = acc / fmaxf(s, 1e-9f) + bias[t];
    o = (o > 0.f) ? o : (__expf(o) - 1.f);  // ELU(alpha=1)
    out[n * 128 + t] = o;
}

// ---------------------------------------------------------------- layer-2 gather: aggregate + bias + head-mean
__global__ void gat_gather2(const float* __restrict__ feat, const __half* __restrict__ w,
                            const int* __restrict__ row_ptr, const int* __restrict__ e_src,
                            const float* __restrict__ bias, float* __restrict__ out) {
    const int n = blockIdx.x;
    const int t = threadIdx.x;      // 192 threads, 188 active: t = h*47 + d
    __shared__ float tmp[192];
    float o = 0.f;
    if (t < 188) {
        const int h = t / 47;
        const int start = row_ptr[n];
        const int end = row_ptr[n + 1];
        float s = 0.f, acc = 0.f;
        int i = start;
        for (; i + 4 <= end; i += 4) {
            int sv0 = e_src[i + 0];
            int sv1 = e_src[i + 1];
            int sv2 = e_src[i + 2];
            int sv3 = e_src[i + 3];
            float w0 = __half2float(w[(i + 0) * 4 + h]);
            float w1 = __half2float(w[(i + 1) * 4 + h]);
            float w2 = __half2float(w[(i + 2) * 4 + h]);
            float w3 = __half2float(w[(i + 3) * 4 + h]);
            float f0 = feat[(size_t)sv0 * 188 + t];
            float f1 = feat[(size_t)sv1 * 188 + t];
            float f2 = feat[(size_t)sv2 * 188 + t];
            float f3 = feat[(size_t)sv3 * 188 + t];
            s += (w0 + w1) + (w2 + w3);
            acc += w0 * f0;
            acc += w1 * f1;
            acc += w2 * f2;
            acc += w3 * f3;
        }
        for (; i < end; ++i) {
            int sv = e_src[i];
            float ww = __half2float(w[i * 4 + h]);
            s += ww;
            acc += ww * feat[(size_t)sv * 188 + t];
        }
        o = acc / fmaxf(s, 1e-9f) + bias[t];
    }
    tmp[t] = o;
    __syncthreads();
    if (t < 47)
        out[n * 47 + t] = 0.25f * (tmp[t] + tmp[t + 47] + tmp[t + 94] + tmp[t + 141]);
}

// ---------------------------------------------------------------- launcher
extern "C" void kernel_launch(void* const* d_in, const int* in_sizes, int n_in,
                              void* d_out, int out_size, void* d_ws, size_t ws_size,
                              hipStream_t stream) {
    const int N = N_NODES, E = N_EDGES;
    const float* x    = (const float*)d_in[0];
    const int*   src  = (const int*)d_in[1];
    const int*   dst  = (const int*)d_in[2];
    const int*   inv  = (const int*)d_in[3];
    const float* W1   = (const float*)d_in[4];
    const float* al1  = (const float*)d_in[5];
    const float* ar1  = (const float*)d_in[6];
    const float* b1   = (const float*)d_in[7];
    const float* W2   = (const float*)d_in[8];
    const float* al2  = (const float*)d_in[9];
    const float* ar2  = (const float*)d_in[10];
    const float* b2   = (const float*)d_in[11];
    float* out = (float*)d_out;

    // workspace carve (all 256B-aligned)
    char* p = (char*)d_ws;
    auto carve = [&](size_t bytes) {
        char* q = p;
        p += (bytes + 255) & ~size_t(255);
        return q;
    };
    float*  feat    = (float*)carve((size_t)N * 188 * 4);  // layer1 stride 128, layer2 stride 188
    float*  hbuf    = (float*)carve((size_t)N * 128 * 4);
    float*  el      = (float*)carve((size_t)N * 4 * 4);
    float*  er      = (float*)carve((size_t)N * 4 * 4);
    int*    deg     = (int*)carve((size_t)N * 4);
    int*    row_ptr = (int*)carve((size_t)(N + 1) * 4);
    int*    cursor  = (int*)carve((size_t)N * 4);
    int*    e_src   = (int*)carve((size_t)E * 4);
    int*    e_dst   = (int*)carve((size_t)E * 4);
    __half* ew      = (__half*)carve((size_t)E * 4 * 2);

    // ---- CSR build (per launch; ws is re-poisoned each call) ----
    zero_int<<<(N + 255) / 256, 256, 0, stream>>>(deg, N);
    count_deg<<<(E + 255) / 256, 256, 0, stream>>>(dst, deg, E);
    scan_deg<<<1, 1024, 0, stream>>>(deg, row_ptr, N);
    copy_int<<<(N + 255) / 256, 256, 0, stream>>>(row_ptr, cursor, N);
    scatter_edges<<<(E + 255) / 256, 256, 0, stream>>>(src, dst, cursor, e_src, e_dst, E);

    // ---- layer 1 ----
    gemm_x128<128, 64><<<(N + 15) / 16, 64, 0, stream>>>(x, W1, feat, nullptr, N);
    compute_elr<4, 32, 128, 128, 32><<<N, 128, 0, stream>>>(feat, al1, ar1, el, er);
    edge_weights<<<(E + 255) / 256, 256, 0, stream>>>(e_src, e_dst, el, er, ew, E);
    gat_gather1<<<N, 128, 0, stream>>>(feat, ew, row_ptr, e_src, b1, hbuf);

    // ---- layer 2 (input rows gathered through inverse_idx) ----
    gemm_x128<188, 128><<<(N + 15) / 16, 128, 0, stream>>>(hbuf, W2, feat, inv, N);
    compute_elr<4, 47, 188, 192, 64><<<N, 192, 0, stream>>>(feat, al2, ar2, el, er);
    edge_weights<<<(E + 255) / 256, 256, 0, stream>>>(e_src, e_dst, el, er, ew, E);
    gat_gather2<<<N, 192, 0, stream>>>(feat, ew, row_ptr, e_src, b2, out);
}

// Round 3
// 827.077 us; speedup vs baseline: 1.4201x; 1.2061x over previous
//
#include <hip/hip_runtime.h>
#include <hip/hip_bf16.h>
#include <hip/hip_fp16.h>
#include <type_traits>

#define N_NODES 100000
#define N_EDGES 1600000

// ---------------------------------------------------------------- CSR build
__global__ void zero_int(int* p, int n) {
    int i = blockIdx.x * blockDim.x + threadIdx.x;
    if (i < n) p[i] = 0;
}

__global__ void count_deg(const int* __restrict__ dst, int* __restrict__ deg, int E) {
    int i = blockIdx.x * blockDim.x + threadIdx.x;
    if (i < E) atomicAdd(&deg[dst[i]], 1);
}

// per-256-block sums of deg
__global__ void block_sums(const int* __restrict__ deg, int* __restrict__ bsum, int N) {
    __shared__ int ws[4];
    const int t = threadIdx.x;
    int i = blockIdx.x * 256 + t;
    int v = (i < N) ? deg[i] : 0;
    #pragma unroll
    for (int o = 32; o; o >>= 1) v += __shfl_down(v, o, 64);
    if ((t & 63) == 0) ws[t >> 6] = v;
    __syncthreads();
    if (t == 0) bsum[blockIdx.x] = ws[0] + ws[1] + ws[2] + ws[3];
}

// inclusive scan of bsum (nb <= 512), single block of 512
__global__ void scan_bsum(int* __restrict__ bsum, int nb) {
    __shared__ int sh[512];
    const int t = threadIdx.x;
    sh[t] = (t < nb) ? bsum[t] : 0;
    __syncthreads();
    for (int o = 1; o < 512; o <<= 1) {
        int v = (t >= o) ? sh[t - o] : 0;
        __syncthreads();
        sh[t] += v;
        __syncthreads();
    }
    if (t < nb) bsum[t] = sh[t];
}

// per-block scan of deg + block offset -> row_ptr (and cursor = exclusive prefix)
__global__ void scan_final(const int* __restrict__ deg, const int* __restrict__ bsum,
                           int* __restrict__ row_ptr, int* __restrict__ cursor, int N) {
    __shared__ int ws[4];
    const int t = threadIdx.x;
    const int b = blockIdx.x;
    const int i = b * 256 + t;
    const int lane = t & 63;
    const int wid = t >> 6;
    int v = (i < N) ? deg[i] : 0;
    int x = v;
    #pragma unroll
    for (int o = 1; o < 64; o <<= 1) {
        int y = __shfl_up(x, o, 64);
        if (lane >= o) x += y;
    }
    if (lane == 63) ws[wid] = x;
    __syncthreads();
    int prefix = (b > 0) ? bsum[b - 1] : 0;
    for (int k = 0; k < wid; ++k) prefix += ws[k];
    if (i < N) {
        row_ptr[i + 1] = prefix + x;
        cursor[i] = prefix + x - v;
    }
    if (i == 0) row_ptr[0] = 0;
}

__global__ void scatter_edges(const int* __restrict__ src, const int* __restrict__ dst,
                              int* __restrict__ cursor, int* __restrict__ e_src,
                              int* __restrict__ e_dst, int E) {
    int i = blockIdx.x * blockDim.x + threadIdx.x;
    if (i < E) {
        int d = dst[i];
        int p = atomicAdd(&cursor[d], 1);
        e_src[p] = src[i];
        e_dst[p] = d;
    }
}

// ---------------------------------------------------------------- GEMM  C[N,K] = A[gather,0:128] @ W[128,K], fp16 out
template <int K, int NT, typename AT>
__global__ void gemm_x128(const AT* __restrict__ A, const float* __restrict__ W,
                          __half* __restrict__ C, const int* __restrict__ gather, int N) {
    constexpr int ROWS = 16;
    constexpr int COLS = (K + NT - 1) / NT;
    __shared__ float4 As[ROWS][32];
    __shared__ int ridx[ROWS];
    const int tid = threadIdx.x;
    const int r0 = blockIdx.x * ROWS;

    if (tid < ROWS) {
        int row = r0 + tid;
        int pr = 0;
        if (row < N) pr = gather ? gather[row] : row;
        ridx[tid] = pr;
    }
    __syncthreads();
    #pragma unroll
    for (int i = tid; i < ROWS * 32; i += NT) {
        int r = i >> 5, k4 = i & 31;
        if constexpr (std::is_same<AT, float>::value) {
            As[r][k4] = ((const float4*)A)[(size_t)ridx[r] * 32 + k4];
        } else {
            const __half2* A2 = (const __half2*)A;
            __half2 p0 = A2[(size_t)ridx[r] * 64 + k4 * 2 + 0];
            __half2 p1 = A2[(size_t)ridx[r] * 64 + k4 * 2 + 1];
            float2 f0 = __half22float2(p0);
            float2 f1 = __half22float2(p1);
            As[r][k4] = make_float4(f0.x, f0.y, f1.x, f1.y);
        }
    }
    __syncthreads();

    float acc[COLS][ROWS];
    #pragma unroll
    for (int j = 0; j < COLS; ++j)
        #pragma unroll
        for (int r = 0; r < ROWS; ++r) acc[j][r] = 0.f;

    int c[COLS];
    #pragma unroll
    for (int j = 0; j < COLS; ++j) c[j] = tid + j * NT;

    for (int k4 = 0; k4 < 32; ++k4) {
        float w[COLS][4];
        #pragma unroll
        for (int j = 0; j < COLS; ++j)
            #pragma unroll
            for (int jj = 0; jj < 4; ++jj)
                w[j][jj] = (c[j] < K) ? W[(k4 * 4 + jj) * K + c[j]] : 0.f;
        #pragma unroll
        for (int r = 0; r < ROWS; ++r) {
            float4 a = As[r][k4];
            #pragma unroll
            for (int j = 0; j < COLS; ++j) {
                acc[j][r] += a.x * w[j][0];
                acc[j][r] += a.y * w[j][1];
                acc[j][r] += a.z * w[j][2];
                acc[j][r] += a.w * w[j][3];
            }
        }
    }

    #pragma unroll
    for (int r = 0; r < ROWS; ++r) {
        int row = r0 + r;
        if (row < N) {
            #pragma unroll
            for (int j = 0; j < COLS; ++j)
                if (c[j] < K) C[(size_t)row * K + c[j]] = __float2half(acc[j][r]);
        }
    }
}

// ---------------------------------------------------------------- per-node attention dot products (fp16 feat)
template <int H, int D, int HD, int HDP, int P2>
__global__ void compute_elr(const __half* __restrict__ feat, const float* __restrict__ al,
                            const float* __restrict__ ar, float* __restrict__ el,
                            float* __restrict__ er) {
    const int n = blockIdx.x;
    const int t = threadIdx.x;
    __shared__ float sa[HDP], sb[HDP];
    float f = 0.f, a = 0.f, b = 0.f;
    if (t < HD) {
        f = __half2float(feat[(size_t)n * HD + t]);
        a = al[t];
        b = ar[t];
    }
    sa[t] = f * a;
    sb[t] = f * b;
    for (int s = P2 / 2; s >= 1; s >>= 1) {
        __syncthreads();
        if (t < HD) {
            int d = t % D;
            if (d < s && d + s < D) {
                sa[t] += sa[t + s];
                sb[t] += sb[t + s];
            }
        }
    }
    __syncthreads();
    if (t < HD && (t % D) == 0) {
        int h = t / D;
        el[n * H + h] = sa[t];
        er[n * H + h] = sb[t];
    }
}

// ---------------------------------------------------------------- per-edge attention weights (CSR order, fp16)
__global__ void edge_weights(const int* __restrict__ e_src, const int* __restrict__ e_dst,
                             const float* __restrict__ el, const float* __restrict__ er,
                             __half* __restrict__ w, int E) {
    int i = blockIdx.x * blockDim.x + threadIdx.x;
    if (i >= E) return;
    int s = e_src[i], d = e_dst[i];
    float4 a = ((const float4*)el)[s];
    float4 b = ((const float4*)er)[d];
    float e0 = a.x + b.x; e0 = (e0 > 0.f) ? e0 : 0.2f * e0;
    float e1 = a.y + b.y; e1 = (e1 > 0.f) ? e1 : 0.2f * e1;
    float e2 = a.z + b.z; e2 = (e2 > 0.f) ? e2 : 0.2f * e2;
    float e3 = a.w + b.w; e3 = (e3 > 0.f) ? e3 : 0.2f * e3;
    __half2* w2 = (__half2*)w;
    w2[i * 2 + 0] = __floats2half2_rn(__expf(e0), __expf(e1));
    w2[i * 2 + 1] = __floats2half2_rn(__expf(e2), __expf(e3));
}

// ---------------------------------------------------------------- layer-1 gather: weighted aggregate + bias + ELU
__global__ void gat_gather1(const __half* __restrict__ feat, const __half* __restrict__ w,
                            const int* __restrict__ row_ptr, const int* __restrict__ e_src,
                            const float* __restrict__ bias, __half* __restrict__ out) {
    const int n = blockIdx.x;
    const int t = threadIdx.x;      // 128 threads, t = h*32 + d
    const int h = t >> 5;
    const int start = row_ptr[n];
    const int end = row_ptr[n + 1];
    float s = 0.f, acc = 0.f;
    int i = start;
    for (; i + 8 <= end; i += 8) {
        int sv[8];
        float wv[8], fv[8];
        #pragma unroll
        for (int j = 0; j < 8; ++j) sv[j] = e_src[i + j];
        #pragma unroll
        for (int j = 0; j < 8; ++j) wv[j] = __half2float(w[(i + j) * 4 + h]);
        #pragma unroll
        for (int j = 0; j < 8; ++j) fv[j] = __half2float(feat[(size_t)sv[j] * 128 + t]);
        #pragma unroll
        for (int j = 0; j < 8; ++j) { s += wv[j]; acc += wv[j] * fv[j]; }
    }
    for (; i < end; ++i) {
        int sv = e_src[i];
        float ww = __half2float(w[i * 4 + h]);
        s += ww;
        acc += ww * __half2float(feat[(size_t)sv * 128 + t]);
    }
    float o = acc / fmaxf(s, 1e-9f) + bias[t];
    o = (o > 0.f) ? o : (__expf(o) - 1.f);  // ELU(alpha=1)
    out[(size_t)n * 128 + t] = __float2half(o);
}

// ---------------------------------------------------------------- layer-2 gather: aggregate + bias + head-mean
__global__ void gat_gather2(const __half* __restrict__ feat, const __half* __restrict__ w,
                            const int* __restrict__ row_ptr, const int* __restrict__ e_src,
                            const float* __restrict__ bias, float* __restrict__ out) {
    const int n = blockIdx.x;
    const int t = threadIdx.x;      // 192 threads, 188 active: t = h*47 + d
    __shared__ float tmp[192];
    float o = 0.f;
    if (t < 188) {
        const int h = t / 47;
        const int start = row_ptr[n];
        const int end = row_ptr[n + 1];
        float s = 0.f, acc = 0.f;
        int i = start;
        for (; i + 8 <= end; i += 8) {
            int sv[8];
            float wv[8], fv[8];
            #pragma unroll
            for (int j = 0; j < 8; ++j) sv[j] = e_src[i + j];
            #pragma unroll
            for (int j = 0; j < 8; ++j) wv[j] = __half2float(w[(i + j) * 4 + h]);
            #pragma unroll
            for (int j = 0; j < 8; ++j) fv[j] = __half2float(feat[(size_t)sv[j] * 188 + t]);
            #pragma unroll
            for (int j = 0; j < 8; ++j) { s += wv[j]; acc += wv[j] * fv[j]; }
        }
        for (; i < end; ++i) {
            int sv = e_src[i];
            float ww = __half2float(w[i * 4 + h]);
            s += ww;
            acc += ww * __half2float(feat[(size_t)sv * 188 + t]);
        }
        o = acc / fmaxf(s, 1e-9f) + bias[t];
    }
    tmp[t] = o;
    __syncthreads();
    if (t < 47)
        out[n * 47 + t] = 0.25f * (tmp[t] + tmp[t + 47] + tmp[t + 94] + tmp[t + 141]);
}

// ---------------------------------------------------------------- launcher
extern "C" void kernel_launch(void* const* d_in, const int* in_sizes, int n_in,
                              void* d_out, int out_size, void* d_ws, size_t ws_size,
                              hipStream_t stream) {
    const int N = N_NODES, E = N_EDGES;
    const float* x    = (const float*)d_in[0];
    const int*   src  = (const int*)d_in[1];
    const int*   dst  = (const int*)d_in[2];
    const int*   inv  = (const int*)d_in[3];
    const float* W1   = (const float*)d_in[4];
    const float* al1  = (const float*)d_in[5];
    const float* ar1  = (const float*)d_in[6];
    const float* b1   = (const float*)d_in[7];
    const float* W2   = (const float*)d_in[8];
    const float* al2  = (const float*)d_in[9];
    const float* ar2  = (const float*)d_in[10];
    const float* b2   = (const float*)d_in[11];
    float* out = (float*)d_out;

    // workspace carve (all 256B-aligned)
    char* p = (char*)d_ws;
    auto carve = [&](size_t bytes) {
        char* q = p;
        p += (bytes + 255) & ~size_t(255);
        return q;
    };
    __half* feat    = (__half*)carve((size_t)N * 188 * 2);  // layer1 stride 128, layer2 stride 188
    __half* hbuf    = (__half*)carve((size_t)N * 128 * 2);
    float*  el      = (float*)carve((size_t)N * 4 * 4);
    float*  er      = (float*)carve((size_t)N * 4 * 4);
    int*    deg     = (int*)carve((size_t)N * 4);
    int*    row_ptr = (int*)carve((size_t)(N + 1) * 4);
    int*    cursor  = (int*)carve((size_t)N * 4);
    int*    bsum    = (int*)carve(512 * 4);
    int*    e_src   = (int*)carve((size_t)E * 4);
    int*    e_dst   = (int*)carve((size_t)E * 4);
    __half* ew      = (__half*)carve((size_t)E * 4 * 2);

    const int nb = (N + 255) / 256;  // 391

    // ---- CSR build (per launch; ws is re-poisoned each call) ----
    zero_int<<<nb, 256, 0, stream>>>(deg, N);
    count_deg<<<(E + 255) / 256, 256, 0, stream>>>(dst, deg, E);
    block_sums<<<nb, 256, 0, stream>>>(deg, bsum, N);
    scan_bsum<<<1, 512, 0, stream>>>(bsum, nb);
    scan_final<<<nb, 256, 0, stream>>>(deg, bsum, row_ptr, cursor, N);
    scatter_edges<<<(E + 255) / 256, 256, 0, stream>>>(src, dst, cursor, e_src, e_dst, E);

    // ---- layer 1 ----
    gemm_x128<128, 64, float><<<(N + 15) / 16, 64, 0, stream>>>(x, W1, feat, nullptr, N);
    compute_elr<4, 32, 128, 128, 32><<<N, 128, 0, stream>>>(feat, al1, ar1, el, er);
    edge_weights<<<(E + 255) / 256, 256, 0, stream>>>(e_src, e_dst, el, er, ew, E);
    gat_gather1<<<N, 128, 0, stream>>>(feat, ew, row_ptr, e_src, b1, hbuf);

    // ---- layer 2 (input rows gathered through inverse_idx) ----
    gemm_x128<188, 128, __half><<<(N + 15) / 16, 128, 0, stream>>>(hbuf, W2, feat, inv, N);
    compute_elr<4, 47, 188, 192, 64><<<N, 192, 0, stream>>>(feat, al2, ar2, el, er);
    edge_weights<<<(E + 255) / 256, 256, 0, stream>>>(e_src, e_dst, el, er, ew, E);
    gat_gather2<<<N, 192, 0, stream>>>(feat, ew, row_ptr, e_src, b2, out);
}

// Round 4
// 665.065 us; speedup vs baseline: 1.7661x; 1.2436x over previous
//
#include <hip/hip_runtime.h>
#include <hip/hip_bf16.h>
#include <hip/hip_fp16.h>
#include <type_traits>

#define N_NODES 100000
#define N_EDGES 1600000

typedef _Float16 half8_t __attribute__((ext_vector_type(8)));
typedef _Float16 half4_t __attribute__((ext_vector_type(4)));
typedef float floatx4 __attribute__((ext_vector_type(4)));

// ---------------------------------------------------------------- CSR build
__global__ void zero_int(int* p, int n) {
    int i = blockIdx.x * blockDim.x + threadIdx.x;
    if (i < n) p[i] = 0;
}

__global__ void count_deg(const int* __restrict__ dst, int* __restrict__ deg, int E) {
    int i = blockIdx.x * blockDim.x + threadIdx.x;
    if (i < E) atomicAdd(&deg[dst[i]], 1);
}

__global__ void block_sums(const int* __restrict__ deg, int* __restrict__ bsum, int N) {
    __shared__ int ws[4];
    const int t = threadIdx.x;
    int i = blockIdx.x * 256 + t;
    int v = (i < N) ? deg[i] : 0;
    #pragma unroll
    for (int o = 32; o; o >>= 1) v += __shfl_down(v, o, 64);
    if ((t & 63) == 0) ws[t >> 6] = v;
    __syncthreads();
    if (t == 0) bsum[blockIdx.x] = ws[0] + ws[1] + ws[2] + ws[3];
}

__global__ void scan_bsum(int* __restrict__ bsum, int nb) {
    __shared__ int sh[512];
    const int t = threadIdx.x;
    sh[t] = (t < nb) ? bsum[t] : 0;
    __syncthreads();
    for (int o = 1; o < 512; o <<= 1) {
        int v = (t >= o) ? sh[t - o] : 0;
        __syncthreads();
        sh[t] += v;
        __syncthreads();
    }
    if (t < nb) bsum[t] = sh[t];
}

__global__ void scan_final(const int* __restrict__ deg, const int* __restrict__ bsum,
                           int* __restrict__ row_ptr, int* __restrict__ cursor, int N) {
    __shared__ int ws[4];
    const int t = threadIdx.x;
    const int b = blockIdx.x;
    const int i = b * 256 + t;
    const int lane = t & 63;
    const int wid = t >> 6;
    int v = (i < N) ? deg[i] : 0;
    int x = v;
    #pragma unroll
    for (int o = 1; o < 64; o <<= 1) {
        int y = __shfl_up(x, o, 64);
        if (lane >= o) x += y;
    }
    if (lane == 63) ws[wid] = x;
    __syncthreads();
    int prefix = (b > 0) ? bsum[b - 1] : 0;
    for (int k = 0; k < wid; ++k) prefix += ws[k];
    if (i < N) {
        row_ptr[i + 1] = prefix + x;
        cursor[i] = prefix + x - v;
    }
    if (i == 0) row_ptr[0] = 0;
}

__global__ void scatter_edges(const int* __restrict__ src, const int* __restrict__ dst,
                              int* __restrict__ cursor, int* __restrict__ e_src,
                              int* __restrict__ e_dst, int E) {
    int i = blockIdx.x * blockDim.x + threadIdx.x;
    if (i < E) {
        int d = dst[i];
        int p = atomicAdd(&cursor[d], 1);
        e_src[p] = src[i];
        e_dst[p] = d;
    }
}

// ---------------------------------------------------------------- W prep: transpose + fp16
// Wt1[c][k] = W1[k][c] (128x128); Wt2[c][k] = W2[k][c] (192x128, cols>=188 zero)
__global__ void prep_w(const float* __restrict__ W1, const float* __restrict__ W2,
                       __half* __restrict__ Wt1, __half* __restrict__ Wt2) {
    const int c = blockIdx.x;
    const int k = threadIdx.x;
    if (c < 128) {
        Wt1[c * 128 + k] = __float2half(W1[k * 128 + c]);
    } else {
        int c2 = c - 128;  // 0..191
        float v = (c2 < 188) ? W2[k * 188 + c2] : 0.f;
        Wt2[c2 * 128 + k] = __float2half(v);
    }
}

// ---------------------------------------------------------------- MFMA GEMM
// C[row, c] = sum_k A[src_row, k] * Wt[c][k],  K=128, fp16 in, fp32 acc, fp16 out.
// Block: 256 thr = 4 waves, 64 rows. Wave w: rows w*16..w*16+15, all NTILES col-tiles.
// Frags (m89-verified): A[m=lane&15][k=quad*8+j]; B[k=quad*8+j][n=lane&15];
//                       C/D: col=lane&15, row=quad*4+reg.
template <int NTILES, int NLOG, int OSTRIDE, bool PADSTORE, bool GATHER, typename AT>
__global__ __launch_bounds__(256) void gemm_mfma(
    const AT* __restrict__ A, const __half* __restrict__ Wt,
    __half* __restrict__ C, const int* __restrict__ gather, int N) {
    constexpr int LDA = 136;             // halfs/row: 128 + 8 pad (272B stride, 2-way bank alias = free)
    __shared__ _Float16 As[64 * LDA];
    __shared__ int ridx[64];
    const int tid = threadIdx.x;
    const int r0 = blockIdx.x * 64;

    if (tid < 64) {
        int row = r0 + tid;
        int pr = 0;
        if (row < N) pr = GATHER ? gather[row] : row;
        ridx[tid] = pr;
    }
    __syncthreads();

    {   // stage A: thread (r = tid>>2, q = tid&3) covers row r, quarter q (32 halfs)
        const int r = tid >> 2, q = tid & 3;
        const int src = ridx[r];
        if constexpr (std::is_same<AT, float>::value) {
            const float4* A4 = (const float4*)A;  // row stride 32 float4
            #pragma unroll
            for (int i = 0; i < 8; ++i) {
                float4 v = A4[(size_t)src * 32 + q * 8 + i];
                half4_t hv = {(_Float16)v.x, (_Float16)v.y, (_Float16)v.z, (_Float16)v.w};
                *(half4_t*)&As[r * LDA + q * 32 + i * 4] = hv;  // ds_write_b64
            }
        } else {
            const uint4* A4 = (const uint4*)A;    // row stride 16 uint4 (128 halfs)
            #pragma unroll
            for (int i = 0; i < 4; ++i) {
                uint4 v = A4[(size_t)src * 16 + q * 4 + i];
                *(uint4*)&As[r * LDA + q * 32 + i * 8] = v;     // ds_write_b128
            }
        }
    }
    __syncthreads();

    const int lane = tid & 63;
    const int wave = tid >> 6;
    const int col = lane & 15;
    const int quad = lane >> 4;
    const int arow = wave * 16 + col;   // A m-index

    floatx4 acc[NTILES];
    #pragma unroll
    for (int t = 0; t < NTILES; ++t) acc[t] = (floatx4){0.f, 0.f, 0.f, 0.f};

    #pragma unroll
    for (int kc = 0; kc < 4; ++kc) {
        half8_t a = *(const half8_t*)&As[arow * LDA + kc * 32 + quad * 8];  // ds_read_b128
        #pragma unroll
        for (int t = 0; t < NTILES; ++t) {
            half8_t b = *(const half8_t*)&Wt[(size_t)(t * 16 + col) * 128 + kc * 32 + quad * 8];
            acc[t] = __builtin_amdgcn_mfma_f32_16x16x32_f16(a, b, acc[t], 0, 0, 0);
        }
    }

    #pragma unroll
    for (int t = 0; t < NTILES; ++t) {
        #pragma unroll
        for (int r = 0; r < 4; ++r) {
            int row = r0 + wave * 16 + quad * 4 + r;
            int c = t * 16 + col;
            if (row < N && c < NLOG) {
                int sc = PADSTORE ? (c + c / 47) : c;   // per-head pad: storage col = h*48+d
                C[(size_t)row * OSTRIDE + sc] = __float2half(acc[t][r]);
            }
        }
    }
}

// ---------------------------------------------------------------- per-node attention dots
// layer 1: feat1 [n][128], heads of 32
template <int H, int D, int HD, int HDP, int P2>
__global__ void compute_elr(const __half* __restrict__ feat, const float* __restrict__ al,
                            const float* __restrict__ ar, float* __restrict__ el,
                            float* __restrict__ er) {
    const int n = blockIdx.x;
    const int t = threadIdx.x;
    __shared__ float sa[HDP], sb[HDP];
    float f = 0.f, a = 0.f, b = 0.f;
    if (t < HD) {
        f = __half2float(feat[(size_t)n * HD + t]);
        a = al[t];
        b = ar[t];
    }
    sa[t] = f * a;
    sb[t] = f * b;
    for (int s = P2 / 2; s >= 1; s >>= 1) {
        __syncthreads();
        if (t < HD) {
            int d = t % D;
            if (d < s && d + s < D) {
                sa[t] += sa[t + s];
                sb[t] += sb[t + s];
            }
        }
    }
    __syncthreads();
    if (t < HD && (t % D) == 0) {
        int h = t / D;
        el[n * H + h] = sa[t];
        er[n * H + h] = sb[t];
    }
}

// layer 2: feat2 padded [n][192] (storage h*48+d), logical heads of 47
__global__ void compute_elr2(const __half* __restrict__ feat, const float* __restrict__ al,
                             const float* __restrict__ ar, float* __restrict__ el,
                             float* __restrict__ er) {
    const int n = blockIdx.x;
    const int t = threadIdx.x;   // 192 threads, 188 active
    __shared__ float sa[192], sb[192];
    float f = 0.f, a = 0.f, b = 0.f;
    if (t < 188) {
        int h = t / 47, d = t - h * 47;
        f = __half2float(feat[(size_t)n * 192 + h * 48 + d]);
        a = al[t];
        b = ar[t];
    }
    sa[t] = f * a;
    sb[t] = f * b;
    for (int s = 32; s >= 1; s >>= 1) {
        __syncthreads();
        if (t < 188) {
            int d = t % 47;
            if (d < s && d + s < 47) {
                sa[t] += sa[t + s];
                sb[t] += sb[t + s];
            }
        }
    }
    __syncthreads();
    if (t < 188 && (t % 47) == 0) {
        int h = t / 47;
        el[n * 4 + h] = sa[t];
        er[n * 4 + h] = sb[t];
    }
}

// ---------------------------------------------------------------- per-edge attention weights (fp16)
__global__ void edge_weights(const int* __restrict__ e_src, const int* __restrict__ e_dst,
                             const float* __restrict__ el, const float* __restrict__ er,
                             __half* __restrict__ w, int E) {
    int i = blockIdx.x * blockDim.x + threadIdx.x;
    if (i >= E) return;
    int s = e_src[i], d = e_dst[i];
    float4 a = ((const float4*)el)[s];
    float4 b = ((const float4*)er)[d];
    float e0 = a.x + b.x; e0 = (e0 > 0.f) ? e0 : 0.2f * e0;
    float e1 = a.y + b.y; e1 = (e1 > 0.f) ? e1 : 0.2f * e1;
    float e2 = a.z + b.z; e2 = (e2 > 0.f) ? e2 : 0.2f * e2;
    float e3 = a.w + b.w; e3 = (e3 > 0.f) ? e3 : 0.2f * e3;
    __half2* w2 = (__half2*)w;
    w2[i * 2 + 0] = __floats2half2_rn(__expf(e0), __expf(e1));
    w2[i * 2 + 1] = __floats2half2_rn(__expf(e2), __expf(e3));
}

// ---------------------------------------------------------------- layer-1 gather: wave/node, 64 lanes x half2
__global__ __launch_bounds__(256) void gat_gather1(
    const __half* __restrict__ feat, const __half* __restrict__ w,
    const int* __restrict__ row_ptr, const int* __restrict__ e_src,
    const float* __restrict__ bias, __half* __restrict__ out) {
    const int t = threadIdx.x;
    const int lane = t & 63;
    const int n = blockIdx.x * 4 + (t >> 6);
    const int h = lane >> 4;                 // 2 dims per lane, 32/head
    const int start = row_ptr[n], end = row_ptr[n + 1];
    const __half2* f2 = (const __half2*)feat;  // row = 64 half2
    float ax = 0.f, ay = 0.f, s = 0.f;
    int i = start;
    for (; i + 4 <= end; i += 4) {
        int sv0 = e_src[i + 0], sv1 = e_src[i + 1], sv2 = e_src[i + 2], sv3 = e_src[i + 3];
        float w0 = __half2float(w[(i + 0) * 4 + h]);
        float w1 = __half2float(w[(i + 1) * 4 + h]);
        float w2 = __half2float(w[(i + 2) * 4 + h]);
        float w3 = __half2float(w[(i + 3) * 4 + h]);
        __half2 f0 = f2[(size_t)sv0 * 64 + lane];
        __half2 f1 = f2[(size_t)sv1 * 64 + lane];
        __half2 f2v = f2[(size_t)sv2 * 64 + lane];
        __half2 f3 = f2[(size_t)sv3 * 64 + lane];
        float2 g0 = __half22float2(f0), g1 = __half22float2(f1);
        float2 g2 = __half22float2(f2v), g3 = __half22float2(f3);
        s += (w0 + w1) + (w2 + w3);
        ax += w0 * g0.x + w1 * g1.x + w2 * g2.x + w3 * g3.x;
        ay += w0 * g0.y + w1 * g1.y + w2 * g2.y + w3 * g3.y;
    }
    for (; i < end; ++i) {
        int sv = e_src[i];
        float ww = __half2float(w[i * 4 + h]);
        float2 g = __half22float2(f2[(size_t)sv * 64 + lane]);
        s += ww;
        ax += ww * g.x;
        ay += ww * g.y;
    }
    float inv = 1.f / fmaxf(s, 1e-9f);
    float ox = ax * inv + bias[lane * 2 + 0];
    float oy = ay * inv + bias[lane * 2 + 1];
    ox = (ox > 0.f) ? ox : (__expf(ox) - 1.f);
    oy = (oy > 0.f) ? oy : (__expf(oy) - 1.f);
    ((__half2*)out)[(size_t)n * 64 + lane] = __floats2half2_rn(ox, oy);
}

// ---------------------------------------------------------------- layer-2 gather: wave/node, 48 lanes x half4 (padded feat2)
__global__ __launch_bounds__(256) void gat_gather2(
    const __half* __restrict__ feat, const __half* __restrict__ w,
    const int* __restrict__ row_ptr, const int* __restrict__ e_src,
    const float* __restrict__ bias, float* __restrict__ out) {
    const int t = threadIdx.x;
    const int lane = t & 63;
    const int n = blockIdx.x * 4 + (t >> 6);
    if (lane < 48) {
        const int h = lane / 12;
        const int q = lane - h * 12;         // half4 index within head (d = q*4..q*4+3)
        const int start = row_ptr[n], end = row_ptr[n + 1];
        const half4_t* f4 = (const half4_t*)feat;  // row = 48 half4
        float a0 = 0.f, a1 = 0.f, a2 = 0.f, a3 = 0.f, s = 0.f;
        int i = start;
        for (; i + 4 <= end; i += 4) {
            int sv0 = e_src[i + 0], sv1 = e_src[i + 1], sv2 = e_src[i + 2], sv3 = e_src[i + 3];
            float w0 = __half2float(w[(i + 0) * 4 + h]);
            float w1 = __half2float(w[(i + 1) * 4 + h]);
            float w2 = __half2float(w[(i + 2) * 4 + h]);
            float w3 = __half2float(w[(i + 3) * 4 + h]);
            half4_t f0 = f4[(size_t)sv0 * 48 + lane];
            half4_t f1 = f4[(size_t)sv1 * 48 + lane];
            half4_t f2 = f4[(size_t)sv2 * 48 + lane];
            half4_t f3 = f4[(size_t)sv3 * 48 + lane];
            s += (w0 + w1) + (w2 + w3);
            a0 += w0 * (float)f0[0] + w1 * (float)f1[0] + w2 * (float)f2[0] + w3 * (float)f3[0];
            a1 += w0 * (float)f0[1] + w1 * (float)f1[1] + w2 * (float)f2[1] + w3 * (float)f3[1];
            a2 += w0 * (float)f0[2] + w1 * (float)f1[2] + w2 * (float)f2[2] + w3 * (float)f3[2];
            a3 += w0 * (float)f0[3] + w1 * (float)f1[3] + w2 * (float)f2[3] + w3 * (float)f3[3];
        }
        for (; i < end; ++i) {
            int sv = e_src[i];
            float ww = __half2float(w[i * 4 + h]);
            half4_t f0 = f4[(size_t)sv * 48 + lane];
            s += ww;
            a0 += ww * (float)f0[0];
            a1 += ww * (float)f0[1];
            a2 += ww * (float)f0[2];
            a3 += ww * (float)f0[3];
        }
        if (q == 11) a3 = 0.f;               // storage pad col (poison) — mask
        float inv = 1.f / fmaxf(s, 1e-9f);
        const int d0 = q * 4;
        float b0 = bias[h * 47 + d0 + 0];
        float b1 = bias[h * 47 + d0 + 1];
        float b2 = bias[h * 47 + d0 + 2];
        float b3 = (d0 + 3 < 47) ? bias[h * 47 + d0 + 3] : 0.f;
        float r0 = a0 * inv + b0;
        float r1 = a1 * inv + b1;
        float r2 = a2 * inv + b2;
        float r3 = a3 * inv + b3;
        // head-mean: lanes q, q+12, q+24, q+36 hold same dims for heads 0..3
        float t0 = r0 + __shfl(r0, lane + 12, 64) + __shfl(r0, lane + 24, 64) + __shfl(r0, lane + 36, 64);
        float t1 = r1 + __shfl(r1, lane + 12, 64) + __shfl(r1, lane + 24, 64) + __shfl(r1, lane + 36, 64);
        float t2 = r2 + __shfl(r2, lane + 12, 64) + __shfl(r2, lane + 24, 64) + __shfl(r2, lane + 36, 64);
        float t3 = r3 + __shfl(r3, lane + 12, 64) + __shfl(r3, lane + 24, 64) + __shfl(r3, lane + 36, 64);
        if (h == 0) {
            size_t base = (size_t)n * 47 + d0;
            out[base + 0] = 0.25f * t0;
            out[base + 1] = 0.25f * t1;
            out[base + 2] = 0.25f * t2;
            if (d0 + 3 < 47) out[base + 3] = 0.25f * t3;
        }
    }
}

// ---------------------------------------------------------------- launcher
extern "C" void kernel_launch(void* const* d_in, const int* in_sizes, int n_in,
                              void* d_out, int out_size, void* d_ws, size_t ws_size,
                              hipStream_t stream) {
    const int N = N_NODES, E = N_EDGES;
    const float* x    = (const float*)d_in[0];
    const int*   src  = (const int*)d_in[1];
    const int*   dst  = (const int*)d_in[2];
    const int*   inv  = (const int*)d_in[3];
    const float* W1   = (const float*)d_in[4];
    const float* al1  = (const float*)d_in[5];
    const float* ar1  = (const float*)d_in[6];
    const float* b1   = (const float*)d_in[7];
    const float* W2   = (const float*)d_in[8];
    const float* al2  = (const float*)d_in[9];
    const float* ar2  = (const float*)d_in[10];
    const float* b2   = (const float*)d_in[11];
    float* out = (float*)d_out;

    char* p = (char*)d_ws;
    auto carve = [&](size_t bytes) {
        char* q = p;
        p += (bytes + 255) & ~size_t(255);
        return q;
    };
    __half* feat1   = (__half*)carve((size_t)N * 128 * 2);
    __half* feat2   = (__half*)carve((size_t)N * 192 * 2);  // per-head padded: storage col h*48+d
    __half* hbuf    = (__half*)carve((size_t)N * 128 * 2);
    __half* Wt1     = (__half*)carve(128 * 128 * 2);
    __half* Wt2     = (__half*)carve(192 * 128 * 2);
    float*  el      = (float*)carve((size_t)N * 4 * 4);
    float*  er      = (float*)carve((size_t)N * 4 * 4);
    int*    deg     = (int*)carve((size_t)N * 4);
    int*    row_ptr = (int*)carve((size_t)(N + 1) * 4);
    int*    cursor  = (int*)carve((size_t)N * 4);
    int*    bsum    = (int*)carve(512 * 4);
    int*    e_src   = (int*)carve((size_t)E * 4);
    int*    e_dst   = (int*)carve((size_t)E * 4);
    __half* ew      = (__half*)carve((size_t)E * 4 * 2);

    const int nb = (N + 255) / 256;  // 391

    // ---- CSR build ----
    zero_int<<<nb, 256, 0, stream>>>(deg, N);
    count_deg<<<(E + 255) / 256, 256, 0, stream>>>(dst, deg, E);
    block_sums<<<nb, 256, 0, stream>>>(deg, bsum, N);
    scan_bsum<<<1, 512, 0, stream>>>(bsum, nb);
    scan_final<<<nb, 256, 0, stream>>>(deg, bsum, row_ptr, cursor, N);
    scatter_edges<<<(E + 255) / 256, 256, 0, stream>>>(src, dst, cursor, e_src, e_dst, E);

    // ---- weight prep ----
    prep_w<<<320, 128, 0, stream>>>(W1, W2, Wt1, Wt2);

    // ---- layer 1 ----
    gemm_mfma<8, 128, 128, false, false, float><<<(N + 63) / 64, 256, 0, stream>>>(x, Wt1, feat1, nullptr, N);
    compute_elr<4, 32, 128, 128, 32><<<N, 128, 0, stream>>>(feat1, al1, ar1, el, er);
    edge_weights<<<(E + 255) / 256, 256, 0, stream>>>(e_src, e_dst, el, er, ew, E);
    gat_gather1<<<(N + 3) / 4, 256, 0, stream>>>(feat1, ew, row_ptr, e_src, b1, hbuf);

    // ---- layer 2 (rows gathered through inverse_idx) ----
    gemm_mfma<12, 188, 192, true, true, __half><<<(N + 63) / 64, 256, 0, stream>>>(hbuf, Wt2, feat2, inv, N);
    compute_elr2<<<N, 192, 0, stream>>>(feat2, al2, ar2, el, er);
    edge_weights<<<(E + 255) / 256, 256, 0, stream>>>(e_src, e_dst, el, er, ew, E);
    gat_gather2<<<(N + 3) / 4, 256, 0, stream>>>(feat2, ew, row_ptr, e_src, b2, out);
}

// Round 5
// 626.975 us; speedup vs baseline: 1.8734x; 1.0608x over previous
//
#include <hip/hip_runtime.h>
#include <hip/hip_bf16.h>
#include <hip/hip_fp16.h>
#include <type_traits>

#define N_NODES 100000
#define N_EDGES 1600000

typedef _Float16 half8_t __attribute__((ext_vector_type(8)));
typedef _Float16 half4_t __attribute__((ext_vector_type(4)));
typedef float floatx4 __attribute__((ext_vector_type(4)));

// ---------------------------------------------------------------- CSR build
__global__ void zero_int(int* p, int n) {
    int i = blockIdx.x * blockDim.x + threadIdx.x;
    if (i < n) p[i] = 0;
}

__global__ void count_deg(const int* __restrict__ dst, int* __restrict__ deg, int E) {
    int i = blockIdx.x * blockDim.x + threadIdx.x;
    if (i < E) atomicAdd(&deg[dst[i]], 1);
}

__global__ void block_sums(const int* __restrict__ deg, int* __restrict__ bsum, int N) {
    __shared__ int ws[4];
    const int t = threadIdx.x;
    int i = blockIdx.x * 256 + t;
    int v = (i < N) ? deg[i] : 0;
    #pragma unroll
    for (int o = 32; o; o >>= 1) v += __shfl_down(v, o, 64);
    if ((t & 63) == 0) ws[t >> 6] = v;
    __syncthreads();
    if (t == 0) bsum[blockIdx.x] = ws[0] + ws[1] + ws[2] + ws[3];
}

__global__ void scan_bsum(int* __restrict__ bsum, int nb) {
    __shared__ int sh[512];
    const int t = threadIdx.x;
    sh[t] = (t < nb) ? bsum[t] : 0;
    __syncthreads();
    for (int o = 1; o < 512; o <<= 1) {
        int v = (t >= o) ? sh[t - o] : 0;
        __syncthreads();
        sh[t] += v;
        __syncthreads();
    }
    if (t < nb) bsum[t] = sh[t];
}

// per-block scan of deg + block offset -> row_ptr, cursor, and csr_dst fill
__global__ void scan_final(const int* __restrict__ deg, const int* __restrict__ bsum,
                           int* __restrict__ row_ptr, int* __restrict__ cursor,
                           int* __restrict__ csr_dst, int N) {
    __shared__ int ws[4];
    const int t = threadIdx.x;
    const int b = blockIdx.x;
    const int i = b * 256 + t;
    const int lane = t & 63;
    const int wid = t >> 6;
    int v = (i < N) ? deg[i] : 0;
    int x = v;
    #pragma unroll
    for (int o = 1; o < 64; o <<= 1) {
        int y = __shfl_up(x, o, 64);
        if (lane >= o) x += y;
    }
    if (lane == 63) ws[wid] = x;
    __syncthreads();
    int prefix = (b > 0) ? bsum[b - 1] : 0;
    for (int k = 0; k < wid; ++k) prefix += ws[k];
    if (i < N) {
        int st = prefix + x - v;
        row_ptr[i + 1] = prefix + x;
        cursor[i] = st;
        for (int j = 0; j < v; ++j) csr_dst[st + j] = i;
    }
    if (i == 0) row_ptr[0] = 0;
}

// XCD-partitioned scatter: partition = blockIdx & 7 (round-robin block->XCD heuristic).
// Each partition's blocks scan the whole edge list but only scatter dst in their range,
// so CSR-line writes stay within one XCD's L2 (kills the 12x cross-XCD write amplification).
__global__ void scatter_edges_part(const int* __restrict__ src, const int* __restrict__ dst,
                                   int* __restrict__ cursor, int* __restrict__ e_src, int E) {
    const int part = blockIdx.x & 7;
    const int sb = blockIdx.x >> 3;
    const int nslices = gridDim.x >> 3;
    const int psz = N_NODES / 8;
    const int lo = part * psz;
    const int hi = (part == 7) ? N_NODES : lo + psz;
    const int begin = (int)((long long)E * sb / nslices);
    const int end = (int)((long long)E * (sb + 1) / nslices);
    for (int i = begin + threadIdx.x; i < end; i += blockDim.x) {
        int d = dst[i];
        if (d >= lo && d < hi) {
            int p = atomicAdd(&cursor[d], 1);
            e_src[p] = src[i];
        }
    }
}

// ---------------------------------------------------------------- W prep: transpose + fp16
__global__ void prep_w(const float* __restrict__ W1, const float* __restrict__ W2,
                       __half* __restrict__ Wt1, __half* __restrict__ Wt2) {
    const int c = blockIdx.x;
    const int k = threadIdx.x;
    if (c < 128) {
        Wt1[c * 128 + k] = __float2half(W1[k * 128 + c]);
    } else {
        int c2 = c - 128;  // 0..191
        float v = (c2 < 188) ? W2[k * 188 + c2] : 0.f;
        Wt2[c2 * 128 + k] = __float2half(v);
    }
}

// ---------------------------------------------------------------- MFMA GEMM
// C[row, c] = sum_k A[src_row, k] * Wt[c][k],  K=128, fp16 in, fp32 acc, fp16 out.
template <int NTILES, int NLOG, int OSTRIDE, bool PADSTORE, bool GATHER, typename AT>
__global__ __launch_bounds__(256) void gemm_mfma(
    const AT* __restrict__ A, const __half* __restrict__ Wt,
    __half* __restrict__ C, const int* __restrict__ gather, int N) {
    constexpr int LDA = 136;
    __shared__ _Float16 As[64 * LDA];
    __shared__ int ridx[64];
    const int tid = threadIdx.x;
    const int r0 = blockIdx.x * 64;

    if (tid < 64) {
        int row = r0 + tid;
        int pr = 0;
        if (row < N) pr = GATHER ? gather[row] : row;
        ridx[tid] = pr;
    }
    __syncthreads();

    {
        const int r = tid >> 2, q = tid & 3;
        const int src = ridx[r];
        if constexpr (std::is_same<AT, float>::value) {
            const float4* A4 = (const float4*)A;
            #pragma unroll
            for (int i = 0; i < 8; ++i) {
                float4 v = A4[(size_t)src * 32 + q * 8 + i];
                half4_t hv = {(_Float16)v.x, (_Float16)v.y, (_Float16)v.z, (_Float16)v.w};
                *(half4_t*)&As[r * LDA + q * 32 + i * 4] = hv;
            }
        } else {
            const uint4* A4 = (const uint4*)A;
            #pragma unroll
            for (int i = 0; i < 4; ++i) {
                uint4 v = A4[(size_t)src * 16 + q * 4 + i];
                *(uint4*)&As[r * LDA + q * 32 + i * 8] = v;
            }
        }
    }
    __syncthreads();

    const int lane = tid & 63;
    const int wave = tid >> 6;
    const int col = lane & 15;
    const int quad = lane >> 4;
    const int arow = wave * 16 + col;

    floatx4 acc[NTILES];
    #pragma unroll
    for (int t = 0; t < NTILES; ++t) acc[t] = (floatx4){0.f, 0.f, 0.f, 0.f};

    #pragma unroll
    for (int kc = 0; kc < 4; ++kc) {
        half8_t a = *(const half8_t*)&As[arow * LDA + kc * 32 + quad * 8];
        #pragma unroll
        for (int t = 0; t < NTILES; ++t) {
            half8_t b = *(const half8_t*)&Wt[(size_t)(t * 16 + col) * 128 + kc * 32 + quad * 8];
            acc[t] = __builtin_amdgcn_mfma_f32_16x16x32_f16(a, b, acc[t], 0, 0, 0);
        }
    }

    #pragma unroll
    for (int t = 0; t < NTILES; ++t) {
        #pragma unroll
        for (int r = 0; r < 4; ++r) {
            int row = r0 + wave * 16 + quad * 4 + r;
            int c = t * 16 + col;
            if (row < N && c < NLOG) {
                int sc = PADSTORE ? (c + c / 47) : c;
                C[(size_t)row * OSTRIDE + sc] = __float2half(acc[t][r]);
            }
        }
    }
}

// ---------------------------------------------------------------- per-node attention dots
template <int H, int D, int HD, int HDP, int P2>
__global__ void compute_elr(const __half* __restrict__ feat, const float* __restrict__ al,
                            const float* __restrict__ ar, float* __restrict__ el,
                            float* __restrict__ er) {
    const int n = blockIdx.x;
    const int t = threadIdx.x;
    __shared__ float sa[HDP], sb[HDP];
    float f = 0.f, a = 0.f, b = 0.f;
    if (t < HD) {
        f = __half2float(feat[(size_t)n * HD + t]);
        a = al[t];
        b = ar[t];
    }
    sa[t] = f * a;
    sb[t] = f * b;
    for (int s = P2 / 2; s >= 1; s >>= 1) {
        __syncthreads();
        if (t < HD) {
            int d = t % D;
            if (d < s && d + s < D) {
                sa[t] += sa[t + s];
                sb[t] += sb[t + s];
            }
        }
    }
    __syncthreads();
    if (t < HD && (t % D) == 0) {
        int h = t / D;
        el[n * H + h] = sa[t];
        er[n * H + h] = sb[t];
    }
}

__global__ void compute_elr2(const __half* __restrict__ feat, const float* __restrict__ al,
                             const float* __restrict__ ar, float* __restrict__ el,
                             float* __restrict__ er) {
    const int n = blockIdx.x;
    const int t = threadIdx.x;
    __shared__ float sa[192], sb[192];
    float f = 0.f, a = 0.f, b = 0.f;
    if (t < 188) {
        int h = t / 47, d = t - h * 47;
        f = __half2float(feat[(size_t)n * 192 + h * 48 + d]);
        a = al[t];
        b = ar[t];
    }
    sa[t] = f * a;
    sb[t] = f * b;
    for (int s = 32; s >= 1; s >>= 1) {
        __syncthreads();
        if (t < 188) {
            int d = t % 47;
            if (d < s && d + s < 47) {
                sa[t] += sa[t + s];
                sb[t] += sb[t + s];
            }
        }
    }
    __syncthreads();
    if (t < 188 && (t % 47) == 0) {
        int h = t / 47;
        el[n * 4 + h] = sa[t];
        er[n * 4 + h] = sb[t];
    }
}

// ---------------------------------------------------------------- per-edge attention weights (CSR order)
__global__ void edge_weights(const int* __restrict__ e_src, const int* __restrict__ csr_dst,
                             const float* __restrict__ el, const float* __restrict__ er,
                             __half* __restrict__ w, int E) {
    int i = blockIdx.x * blockDim.x + threadIdx.x;
    if (i >= E) return;
    int s = e_src[i], d = csr_dst[i];
    float4 a = ((const float4*)el)[s];
    float4 b = ((const float4*)er)[d];
    float e0 = a.x + b.x; e0 = (e0 > 0.f) ? e0 : 0.2f * e0;
    float e1 = a.y + b.y; e1 = (e1 > 0.f) ? e1 : 0.2f * e1;
    float e2 = a.z + b.z; e2 = (e2 > 0.f) ? e2 : 0.2f * e2;
    float e3 = a.w + b.w; e3 = (e3 > 0.f) ? e3 : 0.2f * e3;
    __half2* w2 = (__half2*)w;
    w2[i * 2 + 0] = __floats2half2_rn(__expf(e0), __expf(e1));
    w2[i * 2 + 1] = __floats2half2_rn(__expf(e2), __expf(e3));
}

// ---------------------------------------------------------------- layer-1 gather
__global__ __launch_bounds__(256) void gat_gather1(
    const __half* __restrict__ feat, const __half* __restrict__ w,
    const int* __restrict__ row_ptr, const int* __restrict__ e_src,
    const float* __restrict__ bias, __half* __restrict__ out) {
    const int t = threadIdx.x;
    const int lane = t & 63;
    const int n = blockIdx.x * 4 + (t >> 6);
    const int h = lane >> 4;
    const int start = row_ptr[n], end = row_ptr[n + 1];
    const __half2* f2 = (const __half2*)feat;
    float ax = 0.f, ay = 0.f, s = 0.f;
    int i = start;
    for (; i + 4 <= end; i += 4) {
        int sv0 = e_src[i + 0], sv1 = e_src[i + 1], sv2 = e_src[i + 2], sv3 = e_src[i + 3];
        float w0 = __half2float(w[(i + 0) * 4 + h]);
        float w1 = __half2float(w[(i + 1) * 4 + h]);
        float w2 = __half2float(w[(i + 2) * 4 + h]);
        float w3 = __half2float(w[(i + 3) * 4 + h]);
        __half2 f0 = f2[(size_t)sv0 * 64 + lane];
        __half2 f1 = f2[(size_t)sv1 * 64 + lane];
        __half2 f2v = f2[(size_t)sv2 * 64 + lane];
        __half2 f3 = f2[(size_t)sv3 * 64 + lane];
        float2 g0 = __half22float2(f0), g1 = __half22float2(f1);
        float2 g2 = __half22float2(f2v), g3 = __half22float2(f3);
        s += (w0 + w1) + (w2 + w3);
        ax += w0 * g0.x + w1 * g1.x + w2 * g2.x + w3 * g3.x;
        ay += w0 * g0.y + w1 * g1.y + w2 * g2.y + w3 * g3.y;
    }
    for (; i < end; ++i) {
        int sv = e_src[i];
        float ww = __half2float(w[i * 4 + h]);
        float2 g = __half22float2(f2[(size_t)sv * 64 + lane]);
        s += ww;
        ax += ww * g.x;
        ay += ww * g.y;
    }
    float inv = 1.f / fmaxf(s, 1e-9f);
    float ox = ax * inv + bias[lane * 2 + 0];
    float oy = ay * inv + bias[lane * 2 + 1];
    ox = (ox > 0.f) ? ox : (__expf(ox) - 1.f);
    oy = (oy > 0.f) ? oy : (__expf(oy) - 1.f);
    ((__half2*)out)[(size_t)n * 64 + lane] = __floats2half2_rn(ox, oy);
}

// ---------------------------------------------------------------- layer-2 gather
__global__ __launch_bounds__(256) void gat_gather2(
    const __half* __restrict__ feat, const __half* __restrict__ w,
    const int* __restrict__ row_ptr, const int* __restrict__ e_src,
    const float* __restrict__ bias, float* __restrict__ out) {
    const int t = threadIdx.x;
    const int lane = t & 63;
    const int n = blockIdx.x * 4 + (t >> 6);
    if (lane < 48) {
        const int h = lane / 12;
        const int q = lane - h * 12;
        const int start = row_ptr[n], end = row_ptr[n + 1];
        const half4_t* f4 = (const half4_t*)feat;
        float a0 = 0.f, a1 = 0.f, a2 = 0.f, a3 = 0.f, s = 0.f;
        int i = start;
        for (; i + 4 <= end; i += 4) {
            int sv0 = e_src[i + 0], sv1 = e_src[i + 1], sv2 = e_src[i + 2], sv3 = e_src[i + 3];
            float w0 = __half2float(w[(i + 0) * 4 + h]);
            float w1 = __half2float(w[(i + 1) * 4 + h]);
            float w2 = __half2float(w[(i + 2) * 4 + h]);
            float w3 = __half2float(w[(i + 3) * 4 + h]);
            half4_t f0 = f4[(size_t)sv0 * 48 + lane];
            half4_t f1 = f4[(size_t)sv1 * 48 + lane];
            half4_t f2 = f4[(size_t)sv2 * 48 + lane];
            half4_t f3 = f4[(size_t)sv3 * 48 + lane];
            s += (w0 + w1) + (w2 + w3);
            a0 += w0 * (float)f0[0] + w1 * (float)f1[0] + w2 * (float)f2[0] + w3 * (float)f3[0];
            a1 += w0 * (float)f0[1] + w1 * (float)f1[1] + w2 * (float)f2[1] + w3 * (float)f3[1];
            a2 += w0 * (float)f0[2] + w1 * (float)f1[2] + w2 * (float)f2[2] + w3 * (float)f3[2];
            a3 += w0 * (float)f0[3] + w1 * (float)f1[3] + w2 * (float)f2[3] + w3 * (float)f3[3];
        }
        for (; i < end; ++i) {
            int sv = e_src[i];
            float ww = __half2float(w[i * 4 + h]);
            half4_t f0 = f4[(size_t)sv * 48 + lane];
            s += ww;
            a0 += ww * (float)f0[0];
            a1 += ww * (float)f0[1];
            a2 += ww * (float)f0[2];
            a3 += ww * (float)f0[3];
        }
        if (q == 11) a3 = 0.f;
        float inv = 1.f / fmaxf(s, 1e-9f);
        const int d0 = q * 4;
        float b0 = bias[h * 47 + d0 + 0];
        float b1 = bias[h * 47 + d0 + 1];
        float b2 = bias[h * 47 + d0 + 2];
        float b3 = (d0 + 3 < 47) ? bias[h * 47 + d0 + 3] : 0.f;
        float r0 = a0 * inv + b0;
        float r1 = a1 * inv + b1;
        float r2 = a2 * inv + b2;
        float r3 = a3 * inv + b3;
        float t0 = r0 + __shfl(r0, lane + 12, 64) + __shfl(r0, lane + 24, 64) + __shfl(r0, lane + 36, 64);
        float t1 = r1 + __shfl(r1, lane + 12, 64) + __shfl(r1, lane + 24, 64) + __shfl(r1, lane + 36, 64);
        float t2 = r2 + __shfl(r2, lane + 12, 64) + __shfl(r2, lane + 24, 64) + __shfl(r2, lane + 36, 64);
        float t3 = r3 + __shfl(r3, lane + 12, 64) + __shfl(r3, lane + 24, 64) + __shfl(r3, lane + 36, 64);
        if (h == 0) {
            size_t base = (size_t)n * 47 + d0;
            out[base + 0] = 0.25f * t0;
            out[base + 1] = 0.25f * t1;
            out[base + 2] = 0.25f * t2;
            if (d0 + 3 < 47) out[base + 3] = 0.25f * t3;
        }
    }
}

// ---------------------------------------------------------------- launcher
extern "C" void kernel_launch(void* const* d_in, const int* in_sizes, int n_in,
                              void* d_out, int out_size, void* d_ws, size_t ws_size,
                              hipStream_t stream) {
    const int N = N_NODES, E = N_EDGES;
    const float* x    = (const float*)d_in[0];
    const int*   src  = (const int*)d_in[1];
    const int*   dst  = (const int*)d_in[2];
    const int*   inv  = (const int*)d_in[3];
    const float* W1   = (const float*)d_in[4];
    const float* al1  = (const float*)d_in[5];
    const float* ar1  = (const float*)d_in[6];
    const float* b1   = (const float*)d_in[7];
    const float* W2   = (const float*)d_in[8];
    const float* al2  = (const float*)d_in[9];
    const float* ar2  = (const float*)d_in[10];
    const float* b2   = (const float*)d_in[11];
    float* out = (float*)d_out;

    char* p = (char*)d_ws;
    auto carve = [&](size_t bytes) {
        char* q = p;
        p += (bytes + 255) & ~size_t(255);
        return q;
    };
    __half* feat1   = (__half*)carve((size_t)N * 128 * 2);
    __half* feat2   = (__half*)carve((size_t)N * 192 * 2);
    __half* hbuf    = (__half*)carve((size_t)N * 128 * 2);
    __half* Wt1     = (__half*)carve(128 * 128 * 2);
    __half* Wt2     = (__half*)carve(192 * 128 * 2);
    float*  el      = (float*)carve((size_t)N * 4 * 4);
    float*  er      = (float*)carve((size_t)N * 4 * 4);
    int*    deg     = (int*)carve((size_t)N * 4);
    int*    row_ptr = (int*)carve((size_t)(N + 1) * 4);
    int*    cursor  = (int*)carve((size_t)N * 4);
    int*    bsum    = (int*)carve(512 * 4);
    int*    e_src   = (int*)carve((size_t)E * 4);
    int*    csr_dst = (int*)carve((size_t)E * 4);
    __half* ew      = (__half*)carve((size_t)E * 4 * 2);

    const int nb = (N + 255) / 256;  // 391

    // ---- CSR build ----
    zero_int<<<nb, 256, 0, stream>>>(deg, N);
    count_deg<<<(E + 255) / 256, 256, 0, stream>>>(dst, deg, E);
    block_sums<<<nb, 256, 0, stream>>>(deg, bsum, N);
    scan_bsum<<<1, 512, 0, stream>>>(bsum, nb);
    scan_final<<<nb, 256, 0, stream>>>(deg, bsum, row_ptr, cursor, csr_dst, N);
    scatter_edges_part<<<2048, 256, 0, stream>>>(src, dst, cursor, e_src, E);

    // ---- weight prep ----
    prep_w<<<320, 128, 0, stream>>>(W1, W2, Wt1, Wt2);

    // ---- layer 1 ----
    gemm_mfma<8, 128, 128, false, false, float><<<(N + 63) / 64, 256, 0, stream>>>(x, Wt1, feat1, nullptr, N);
    compute_elr<4, 32, 128, 128, 32><<<N, 128, 0, stream>>>(feat1, al1, ar1, el, er);
    edge_weights<<<(E + 255) / 256, 256, 0, stream>>>(e_src, csr_dst, el, er, ew, E);
    gat_gather1<<<(N + 3) / 4, 256, 0, stream>>>(feat1, ew, row_ptr, e_src, b1, hbuf);

    // ---- layer 2 (rows gathered through inverse_idx) ----
    gemm_mfma<12, 188, 192, true, true, __half><<<(N + 63) / 64, 256, 0, stream>>>(hbuf, Wt2, feat2, inv, N);
    compute_elr2<<<N, 192, 0, stream>>>(feat2, al2, ar2, el, er);
    edge_weights<<<(E + 255) / 256, 256, 0, stream>>>(e_src, csr_dst, el, er, ew, E);
    gat_gather2<<<(N + 3) / 4, 256, 0, stream>>>(feat2, ew, row_ptr, e_src, b2, out);
}